// Round 1
// baseline (59.538 us; speedup 1.0000x reference)
//
#include <hip/hip_runtime.h>

// Problem constants (fixed by reference: B=4, C=32, H=W=24, hid=128, out=32)
#define B_   4
#define C_   32
#define N_   576     // H*W
#define HID  128
#define OUT_ 32
#define TJ   4       // j-tile per block in pair_kernel

// ---------------------------------------------------------------------------
// Kernel A: per-token projections.
//   tokens[b,n,c] = x[(b*C+c)*N + n]
//   px[b,n,f]  = sum_c tok[c] * W1[c,f]
//   pcb[b,n,f] = sum_c tok[c] * W1[C+c,f] + b1[f]
// One 128-thread block per (b,n). W1 (32KB) stays hot in L1/L2.
// ---------------------------------------------------------------------------
__global__ __launch_bounds__(128) void proj_kernel(
    const float* __restrict__ x, const float* __restrict__ W1,
    const float* __restrict__ b1,
    float* __restrict__ px, float* __restrict__ pcb)
{
    const int blk = blockIdx.x;       // 0 .. B*N-1
    const int b = blk / N_;
    const int n = blk % N_;
    const int f = threadIdx.x;        // 0..127

    __shared__ float tok[C_];
    if (f < C_) tok[f] = x[(b * C_ + f) * N_ + n];
    __syncthreads();

    float accx = 0.f, accc = 0.f;
#pragma unroll
    for (int c = 0; c < C_; ++c) {
        const float t = tok[c];
        accx = fmaf(t, W1[c * HID + f], accx);
        accc = fmaf(t, W1[(C_ + c) * HID + f], accc);
    }
    const int base = (b * N_ + n) * HID + f;
    px[base]  = accx;
    pcb[base] = accc + b1[f];
}

// ---------------------------------------------------------------------------
// Kernel B: the O(B*N^2*hid) pairwise relu-sum + fused output GEMM.
//   g[b,j,f] = sum_i relu(px[b,i,f] + pcb[b,j,f])
//   out[b,o,j] = sum_f g[b,j,f]*W2[f,o] + N*b2[o]
// Block = 128 threads (thread f), handles TJ=4 consecutive j values.
// px[b,:,f] streamed coalesced (wave reads 256B contiguous per i).
// ---------------------------------------------------------------------------
__global__ __launch_bounds__(128) void pair_kernel(
    const float* __restrict__ px, const float* __restrict__ pcb,
    const float* __restrict__ W2, const float* __restrict__ b2,
    float* __restrict__ out)
{
    const int jt = blockIdx.x;        // 0 .. N/TJ-1
    const int b  = blockIdx.y;        // 0 .. B-1
    const int f  = threadIdx.x;       // 0..127
    const int j0 = jt * TJ;

    const float c0 = pcb[(b * N_ + j0 + 0) * HID + f];
    const float c1 = pcb[(b * N_ + j0 + 1) * HID + f];
    const float c2 = pcb[(b * N_ + j0 + 2) * HID + f];
    const float c3 = pcb[(b * N_ + j0 + 3) * HID + f];

    float g0 = 0.f, g1 = 0.f, g2 = 0.f, g3 = 0.f;
    const float* __restrict__ pxb = px + (size_t)b * N_ * HID + f;
#pragma unroll 4
    for (int i = 0; i < N_; ++i) {
        const float a = pxb[(size_t)i * HID];
        g0 += fmaxf(a + c0, 0.f);
        g1 += fmaxf(a + c1, 0.f);
        g2 += fmaxf(a + c2, 0.f);
        g3 += fmaxf(a + c3, 0.f);
    }

    __shared__ float gl[TJ][HID];
    gl[0][f] = g0; gl[1][f] = g1; gl[2][f] = g2; gl[3][f] = g3;
    __syncthreads();

    // Epilogue: 128 threads = (o in 0..31) x (jj in 0..3)
    const int o  = threadIdx.x & 31;
    const int jj = threadIdx.x >> 5;
    float acc = 0.f;
#pragma unroll
    for (int h = 0; h < HID; ++h)
        acc = fmaf(gl[jj][h], W2[h * OUT_ + o], acc);   // gl: broadcast, W2: coalesced
    acc += (float)N_ * b2[o];

    const int j = j0 + jj;
    out[((size_t)b * OUT_ + o) * N_ + j] = acc;
}

// ---------------------------------------------------------------------------
extern "C" void kernel_launch(void* const* d_in, const int* in_sizes, int n_in,
                              void* d_out, int out_size, void* d_ws, size_t ws_size,
                              hipStream_t stream)
{
    const float* x  = (const float*)d_in[0];   // (4,32,24,24)
    const float* W1 = (const float*)d_in[1];   // (64,128)
    const float* b1 = (const float*)d_in[2];   // (128,)
    const float* W2 = (const float*)d_in[3];   // (128,32)
    const float* b2 = (const float*)d_in[4];   // (32,)
    float* out = (float*)d_out;                // (4,32,24,24) fp32

    float* px  = (float*)d_ws;                 // B*N*HID floats
    float* pcb = px + (size_t)B_ * N_ * HID;   // B*N*HID floats  (pc + b1)

    proj_kernel<<<B_ * N_, 128, 0, stream>>>(x, W1, b1, px, pcb);
    pair_kernel<<<dim3(N_ / TJ, B_), 128, 0, stream>>>(px, pcb, W2, b2, out);
}

// Round 2
// 39.610 us; speedup vs baseline: 1.5031x; 1.5031x over previous
//
#include <hip/hip_runtime.h>

// Problem constants (fixed by reference: B=4, C=32, H=W=24, hid=128, out=32)
#define B_     4
#define C_     32
#define N_     576     // H*W
#define HID    128
#define OUT_   32
#define TJ     8       // j's per block in pair_partial (8 groups of 32 lanes)
#define ISPLIT 6       // i-range split for occupancy
#define ICH    (N_ / ISPLIT)   // 96 i's per block

// ---------------------------------------------------------------------------
// Kernel A: per-token projections.
//   tokens[b,n,c] = x[(b*C+c)*N + n]
//   px[b,n,f]  = sum_c tok[c] * W1[c,f]
//   pcb[b,n,f] = sum_c tok[c] * W1[C+c,f] + b1[f]
// ---------------------------------------------------------------------------
__global__ __launch_bounds__(128) void proj_kernel(
    const float* __restrict__ x, const float* __restrict__ W1,
    const float* __restrict__ b1,
    float* __restrict__ px, float* __restrict__ pcb)
{
    const int blk = blockIdx.x;       // 0 .. B*N-1
    const int b = blk / N_;
    const int n = blk % N_;
    const int f = threadIdx.x;        // 0..127

    __shared__ float tok[C_];
    if (f < C_) tok[f] = x[(b * C_ + f) * N_ + n];
    __syncthreads();

    float accx = 0.f, accc = 0.f;
#pragma unroll
    for (int c = 0; c < C_; ++c) {
        const float t = tok[c];
        accx = fmaf(t, W1[c * HID + f], accx);
        accc = fmaf(t, W1[(C_ + c) * HID + f], accc);
    }
    const int base = (b * N_ + n) * HID + f;
    px[base]  = accx;
    pcb[base] = accc + b1[f];
}

// ---------------------------------------------------------------------------
// Kernel B: partial pairwise relu-sum.
//   gpart[b,isp,j,f] = sum_{i in chunk(isp)} relu(px[b,i,f] + pcb[b,j,f])
// Block = 256 threads = 8 groups x 32 lanes. Group owns one j; lane owns
// a float4 of features. 1728 blocks -> ~27 waves/CU.
// ---------------------------------------------------------------------------
__global__ __launch_bounds__(256, 8) void pair_partial(
    const float* __restrict__ px, const float* __restrict__ pcb,
    float* __restrict__ gpart)
{
    const int jt   = blockIdx.x;          // 0 .. N/TJ-1  (72)
    const int isp  = blockIdx.y;          // 0 .. ISPLIT-1
    const int b    = blockIdx.z;          // 0 .. B-1
    const int lane = threadIdx.x & 31;    // f-quad index
    const int grp  = threadIdx.x >> 5;    // 0..7
    const int j    = jt * TJ + grp;

    const float4 c4 = *(const float4*)(pcb + ((size_t)b * N_ + j) * HID + 4 * lane);

    const float* __restrict__ p = px + ((size_t)b * N_ + isp * ICH) * HID + 4 * lane;
    float4 acc = make_float4(0.f, 0.f, 0.f, 0.f);
#pragma unroll 8
    for (int i = 0; i < ICH; ++i) {
        const float4 a = *(const float4*)(p + (size_t)i * HID);
        acc.x += fmaxf(a.x + c4.x, 0.f);
        acc.y += fmaxf(a.y + c4.y, 0.f);
        acc.z += fmaxf(a.z + c4.z, 0.f);
        acc.w += fmaxf(a.w + c4.w, 0.f);
    }

    *(float4*)(gpart + (((size_t)b * ISPLIT + isp) * N_ + j) * HID + 4 * lane) = acc;
}

// ---------------------------------------------------------------------------
// Kernel C: reduce partials + output GEMM.
//   g[b,j,f] = sum_isp gpart[b,isp,j,f]
//   out[b,o,j] = sum_f g[b,j,f]*W2[f,o] + N*b2[o]
// ---------------------------------------------------------------------------
__global__ __launch_bounds__(128) void finish_kernel(
    const float* __restrict__ gpart, const float* __restrict__ W2,
    const float* __restrict__ b2, float* __restrict__ out)
{
    const int jt = blockIdx.x;    // 0 .. N/4-1
    const int b  = blockIdx.y;
    const int f  = threadIdx.x;   // 0..127
    const int j0 = jt * 4;

    __shared__ float gl[4][HID];
#pragma unroll
    for (int jj = 0; jj < 4; ++jj) {
        float s = 0.f;
#pragma unroll
        for (int isp = 0; isp < ISPLIT; ++isp)
            s += gpart[(((size_t)b * ISPLIT + isp) * N_ + j0 + jj) * HID + f];
        gl[jj][f] = s;
    }
    __syncthreads();

    const int o  = threadIdx.x & 31;
    const int jj = threadIdx.x >> 5;
    float acc = 0.f;
#pragma unroll
    for (int h = 0; h < HID; ++h)
        acc = fmaf(gl[jj][h], W2[h * OUT_ + o], acc);   // gl: broadcast, W2: coalesced
    acc += (float)N_ * b2[o];

    out[((size_t)b * OUT_ + o) * N_ + j0 + jj] = acc;
}

// ---------------------------------------------------------------------------
extern "C" void kernel_launch(void* const* d_in, const int* in_sizes, int n_in,
                              void* d_out, int out_size, void* d_ws, size_t ws_size,
                              hipStream_t stream)
{
    const float* x  = (const float*)d_in[0];   // (4,32,24,24)
    const float* W1 = (const float*)d_in[1];   // (64,128)
    const float* b1 = (const float*)d_in[2];   // (128,)
    const float* W2 = (const float*)d_in[3];   // (128,32)
    const float* b2 = (const float*)d_in[4];   // (32,)
    float* out = (float*)d_out;                // (4,32,24,24) fp32

    float* px    = (float*)d_ws;                       // B*N*HID
    float* pcb   = px  + (size_t)B_ * N_ * HID;        // B*N*HID
    float* gpart = pcb + (size_t)B_ * N_ * HID;        // B*ISPLIT*N*HID (~7.1 MB)

    proj_kernel<<<B_ * N_, 128, 0, stream>>>(x, W1, b1, px, pcb);
    pair_partial<<<dim3(N_ / TJ, ISPLIT, B_), 256, 0, stream>>>(px, pcb, gpart);
    finish_kernel<<<dim3(N_ / 4, B_), 128, 0, stream>>>(gpart, W2, b2, out);
}

// Round 3
// 37.636 us; speedup vs baseline: 1.5819x; 1.0524x over previous
//
#include <hip/hip_runtime.h>

// Problem constants (fixed by reference: B=4, C=32, H=W=24, hid=128, out=32)
#define B_     4
#define C_     32
#define N_     576     // H*W
#define HID    128
#define OUT_   32
#define JPT    4       // j's per THREAD (register-tiled)
#define GRPS   8       // 32-lane groups per block
#define TJB    (JPT * GRPS)     // 32 j's per block
#define ISPLIT 12      // i-range split for occupancy
#define ICH    (N_ / ISPLIT)    // 48 i's per block

// ---------------------------------------------------------------------------
// Kernel A: per-token projections.
//   tokens[b,n,c] = x[(b*C+c)*N + n]
//   px[b,n,f]  = sum_c tok[c] * W1[c,f]
//   pcb[b,n,f] = sum_c tok[c] * W1[C+c,f] + b1[f]
// ---------------------------------------------------------------------------
__global__ __launch_bounds__(128) void proj_kernel(
    const float* __restrict__ x, const float* __restrict__ W1,
    const float* __restrict__ b1,
    float* __restrict__ px, float* __restrict__ pcb)
{
    const int blk = blockIdx.x;       // 0 .. B*N-1
    const int b = blk / N_;
    const int n = blk % N_;
    const int f = threadIdx.x;        // 0..127

    __shared__ float tok[C_];
    if (f < C_) tok[f] = x[(b * C_ + f) * N_ + n];
    __syncthreads();

    float accx = 0.f, accc = 0.f;
#pragma unroll
    for (int c = 0; c < C_; ++c) {
        const float t = tok[c];
        accx = fmaf(t, W1[c * HID + f], accx);
        accc = fmaf(t, W1[(C_ + c) * HID + f], accc);
    }
    const int base = (b * N_ + n) * HID + f;
    px[base]  = accx;
    pcb[base] = accc + b1[f];
}

// ---------------------------------------------------------------------------
// Kernel B: partial pairwise relu-sum, register-tiled 4 j's per thread.
//   gpart[b,isp,j,f] = sum_{i in chunk(isp)} relu(px[b,i,f] + pcb[b,j,f])
// Block = 256 threads = 8 groups x 32 lanes; group owns 4 consecutive j's,
// lane owns a float4 of features. One px float4 load feeds 48 VALU ops.
// ---------------------------------------------------------------------------
__global__ __launch_bounds__(256) void pair_partial(
    const float* __restrict__ px, const float* __restrict__ pcb,
    float* __restrict__ gpart)
{
    const int jt   = blockIdx.x;          // 0 .. N/TJB-1  (18)
    const int isp  = blockIdx.y;          // 0 .. ISPLIT-1 (12)
    const int b    = blockIdx.z;          // 0 .. B-1
    const int lane = threadIdx.x & 31;    // f-quad index
    const int grp  = threadIdx.x >> 5;    // 0..7
    const int j0   = jt * TJB + grp * JPT;

    float4 c[JPT];
#pragma unroll
    for (int jp = 0; jp < JPT; ++jp)
        c[jp] = *(const float4*)(pcb + ((size_t)b * N_ + j0 + jp) * HID + 4 * lane);

    float4 acc[JPT];
#pragma unroll
    for (int jp = 0; jp < JPT; ++jp)
        acc[jp] = make_float4(0.f, 0.f, 0.f, 0.f);

    const float* __restrict__ p = px + ((size_t)b * N_ + isp * ICH) * HID + 4 * lane;
#pragma unroll 4
    for (int i = 0; i < ICH; ++i) {
        const float4 a = *(const float4*)(p + (size_t)i * HID);
#pragma unroll
        for (int jp = 0; jp < JPT; ++jp) {
            acc[jp].x += fmaxf(a.x + c[jp].x, 0.f);
            acc[jp].y += fmaxf(a.y + c[jp].y, 0.f);
            acc[jp].z += fmaxf(a.z + c[jp].z, 0.f);
            acc[jp].w += fmaxf(a.w + c[jp].w, 0.f);
        }
    }

#pragma unroll
    for (int jp = 0; jp < JPT; ++jp)
        *(float4*)(gpart + (((size_t)b * ISPLIT + isp) * N_ + j0 + jp) * HID + 4 * lane) = acc[jp];
}

// ---------------------------------------------------------------------------
// Kernel C: reduce partials + output GEMM.
//   g[b,j,f] = sum_isp gpart[b,isp,j,f]
//   out[b,o,j] = sum_f g[b,j,f]*W2[f,o] + N*b2[o]
// ---------------------------------------------------------------------------
__global__ __launch_bounds__(128) void finish_kernel(
    const float* __restrict__ gpart, const float* __restrict__ W2,
    const float* __restrict__ b2, float* __restrict__ out)
{
    const int jt = blockIdx.x;    // 0 .. N/4-1
    const int b  = blockIdx.y;
    const int f  = threadIdx.x;   // 0..127
    const int j0 = jt * 4;

    __shared__ float gl[4][HID];
#pragma unroll
    for (int jj = 0; jj < 4; ++jj) {
        float s = 0.f;
#pragma unroll
        for (int isp = 0; isp < ISPLIT; ++isp)
            s += gpart[(((size_t)b * ISPLIT + isp) * N_ + j0 + jj) * HID + f];
        gl[jj][f] = s;
    }
    __syncthreads();

    const int o  = threadIdx.x & 31;
    const int jj = threadIdx.x >> 5;
    float acc = 0.f;
#pragma unroll
    for (int h = 0; h < HID; ++h)
        acc = fmaf(gl[jj][h], W2[h * OUT_ + o], acc);   // gl: broadcast, W2: coalesced
    acc += (float)N_ * b2[o];

    out[((size_t)b * OUT_ + o) * N_ + j0 + jj] = acc;
}

// ---------------------------------------------------------------------------
extern "C" void kernel_launch(void* const* d_in, const int* in_sizes, int n_in,
                              void* d_out, int out_size, void* d_ws, size_t ws_size,
                              hipStream_t stream)
{
    const float* x  = (const float*)d_in[0];   // (4,32,24,24)
    const float* W1 = (const float*)d_in[1];   // (64,128)
    const float* b1 = (const float*)d_in[2];   // (128,)
    const float* W2 = (const float*)d_in[3];   // (128,32)
    const float* b2 = (const float*)d_in[4];   // (32,)
    float* out = (float*)d_out;                // (4,32,24,24) fp32

    float* px    = (float*)d_ws;                       // B*N*HID
    float* pcb   = px  + (size_t)B_ * N_ * HID;        // B*N*HID
    float* gpart = pcb + (size_t)B_ * N_ * HID;        // B*ISPLIT*N*HID (~14.2 MB)

    proj_kernel<<<B_ * N_, 128, 0, stream>>>(x, W1, b1, px, pcb);
    pair_partial<<<dim3(N_ / TJB, ISPLIT, B_), 256, 0, stream>>>(px, pcb, gpart);
    finish_kernel<<<dim3(N_ / 4, B_), 128, 0, stream>>>(gpart, W2, b2, out);
}

// Round 4
// 36.241 us; speedup vs baseline: 1.6428x; 1.0385x over previous
//
#include <hip/hip_runtime.h>

// Problem constants (fixed by reference: B=4, C=32, H=W=24, hid=128, out=32)
#define B_     4
#define C_     32
#define N_     576     // H*W
#define HID    128
#define OUT_   32
#define JPT    4       // j's per THREAD (register-tiled)
#define GRPS   8       // 32-lane groups per block
#define TJB    (JPT * GRPS)     // 32 j's per block
#define ISPLIT 12      // i-range split for occupancy
#define ICH    (N_ / ISPLIT)    // 48 i's per block
#define STG    (ICH * HID / (256 * 4))   // 6 float4 stages per thread

// ---------------------------------------------------------------------------
// Kernel A: per-token projections.
//   tokens[b,n,c] = x[(b*C+c)*N + n]
//   px[b,n,f]  = sum_c tok[c] * W1[c,f]
//   pcb[b,n,f] = sum_c tok[c] * W1[C+c,f] + b1[f]
// ---------------------------------------------------------------------------
__global__ __launch_bounds__(128) void proj_kernel(
    const float* __restrict__ x, const float* __restrict__ W1,
    const float* __restrict__ b1,
    float* __restrict__ px, float* __restrict__ pcb)
{
    const int blk = blockIdx.x;       // 0 .. B*N-1
    const int b = blk / N_;
    const int n = blk % N_;
    const int f = threadIdx.x;        // 0..127

    __shared__ float tok[C_];
    if (f < C_) tok[f] = x[(b * C_ + f) * N_ + n];
    __syncthreads();

    float accx = 0.f, accc = 0.f;
#pragma unroll
    for (int c = 0; c < C_; ++c) {
        const float t = tok[c];
        accx = fmaf(t, W1[c * HID + f], accx);
        accc = fmaf(t, W1[(C_ + c) * HID + f], accc);
    }
    const int base = (b * N_ + n) * HID + f;
    px[base]  = accx;
    pcb[base] = accc + b1[f];
}

// ---------------------------------------------------------------------------
// Kernel B: partial pairwise relu-sum, LDS-staged px chunk.
//   gpart[b,isp,j,f] = sum_{i in chunk(isp)} relu(px[b,i,f] + pcb[b,j,f])
// Block = 256 threads = 8 groups x 32 lanes; group owns 4 consecutive j's,
// lane owns a float4 of features. px chunk (48 rows x 128 f = 24KB,
// contiguous in memory) is burst-copied to LDS (6 independent float4
// loads/thread -> deep MLP pipelining), then the hot loop runs off LDS.
// ---------------------------------------------------------------------------
__global__ __launch_bounds__(256) void pair_partial(
    const float* __restrict__ px, const float* __restrict__ pcb,
    float* __restrict__ gpart)
{
    const int jt   = blockIdx.x;          // 0 .. N/TJB-1  (18)
    const int isp  = blockIdx.y;          // 0 .. ISPLIT-1 (12)
    const int b    = blockIdx.z;          // 0 .. B-1
    const int tid  = threadIdx.x;
    const int lane = tid & 31;            // f-quad index
    const int grp  = tid >> 5;            // 0..7
    const int j0   = jt * TJB + grp * JPT;

    __shared__ float spx[ICH * HID];      // 24 KB

    // Burst-stage the contiguous px chunk: 6 independent 16B loads/thread.
    const float* __restrict__ src = px + ((size_t)b * N_ + isp * ICH) * HID;
    float4 tmp[STG];
#pragma unroll
    for (int k = 0; k < STG; ++k)
        tmp[k] = *(const float4*)(src + (k * 256 + tid) * 4);

    // pcb for this thread's 4 j's (overlaps with staging latency).
    float4 c[JPT];
#pragma unroll
    for (int jp = 0; jp < JPT; ++jp)
        c[jp] = *(const float4*)(pcb + ((size_t)b * N_ + j0 + jp) * HID + 4 * lane);

#pragma unroll
    for (int k = 0; k < STG; ++k)
        *(float4*)(spx + (k * 256 + tid) * 4) = tmp[k];
    __syncthreads();

    float4 acc[JPT];
#pragma unroll
    for (int jp = 0; jp < JPT; ++jp)
        acc[jp] = make_float4(0.f, 0.f, 0.f, 0.f);

#pragma unroll 4
    for (int i = 0; i < ICH; ++i) {
        const float4 a = *(const float4*)(spx + i * HID + 4 * lane);
#pragma unroll
        for (int jp = 0; jp < JPT; ++jp) {
            acc[jp].x += fmaxf(a.x + c[jp].x, 0.f);
            acc[jp].y += fmaxf(a.y + c[jp].y, 0.f);
            acc[jp].z += fmaxf(a.z + c[jp].z, 0.f);
            acc[jp].w += fmaxf(a.w + c[jp].w, 0.f);
        }
    }

#pragma unroll
    for (int jp = 0; jp < JPT; ++jp)
        *(float4*)(gpart + (((size_t)b * ISPLIT + isp) * N_ + j0 + jp) * HID + 4 * lane) = acc[jp];
}

// ---------------------------------------------------------------------------
// Kernel C: reduce partials + output GEMM.
//   g[b,j,f] = sum_isp gpart[b,isp,j,f]
//   out[b,o,j] = sum_f g[b,j,f]*W2[f,o] + N*b2[o]
// ---------------------------------------------------------------------------
__global__ __launch_bounds__(128) void finish_kernel(
    const float* __restrict__ gpart, const float* __restrict__ W2,
    const float* __restrict__ b2, float* __restrict__ out)
{
    const int jt = blockIdx.x;    // 0 .. N/4-1
    const int b  = blockIdx.y;
    const int f  = threadIdx.x;   // 0..127
    const int j0 = jt * 4;

    __shared__ float gl[4][HID];
#pragma unroll
    for (int jj = 0; jj < 4; ++jj) {
        float s = 0.f;
#pragma unroll
        for (int isp = 0; isp < ISPLIT; ++isp)
            s += gpart[(((size_t)b * ISPLIT + isp) * N_ + j0 + jj) * HID + f];
        gl[jj][f] = s;
    }
    __syncthreads();

    const int o  = threadIdx.x & 31;
    const int jj = threadIdx.x >> 5;
    float acc = 0.f;
#pragma unroll
    for (int h = 0; h < HID; ++h)
        acc = fmaf(gl[jj][h], W2[h * OUT_ + o], acc);   // gl: broadcast, W2: coalesced
    acc += (float)N_ * b2[o];

    out[((size_t)b * OUT_ + o) * N_ + j0 + jj] = acc;
}

// ---------------------------------------------------------------------------
extern "C" void kernel_launch(void* const* d_in, const int* in_sizes, int n_in,
                              void* d_out, int out_size, void* d_ws, size_t ws_size,
                              hipStream_t stream)
{
    const float* x  = (const float*)d_in[0];   // (4,32,24,24)
    const float* W1 = (const float*)d_in[1];   // (64,128)
    const float* b1 = (const float*)d_in[2];   // (128,)
    const float* W2 = (const float*)d_in[3];   // (128,32)
    const float* b2 = (const float*)d_in[4];   // (32,)
    float* out = (float*)d_out;                // (4,32,24,24) fp32

    float* px    = (float*)d_ws;                       // B*N*HID
    float* pcb   = px  + (size_t)B_ * N_ * HID;        // B*N*HID
    float* gpart = pcb + (size_t)B_ * N_ * HID;        // B*ISPLIT*N*HID (~14.2 MB)

    proj_kernel<<<B_ * N_, 128, 0, stream>>>(x, W1, b1, px, pcb);
    pair_partial<<<dim3(N_ / TJB, ISPLIT, B_), 256, 0, stream>>>(px, pcb, gpart);
    finish_kernel<<<dim3(N_ / 4, B_), 128, 0, stream>>>(gpart, W2, b2, out);
}